// Round 1
// baseline (485.121 us; speedup 1.0000x reference)
//
#include <hip/hip_runtime.h>
#include <stdint.h>

#define DEVI __device__ __forceinline__

using bf16x8 = __attribute__((ext_vector_type(8))) __bf16;
using f32x4  = __attribute__((ext_vector_type(4))) float;
using short8 = __attribute__((ext_vector_type(8))) short;

DEVI ushort f2bf(float f){
  uint32_t u = __float_as_uint(f);
  uint32_t r = u + 0x7fffu + ((u >> 16) & 1u);   // RNE
  return (ushort)(r >> 16);
}
DEVI float bf2f(ushort h){ return __uint_as_float(((uint32_t)h) << 16); }

// ---------------------------------------------------------------------------
// NT GEMM: D[m,n] = sum_k A[m,k] * B[n,k]   (A: M x K, B: Nn x K, K-contiguous)
// Tile 128x128, BK=32, 256 threads (4 waves, each 64x64 = 4x4 MFMA 16x16x32).
// SRCMODE: 0=none, 1=add bf16 src, 2=add f32 src.  out = [src +] [relu](acc)
// ---------------------------------------------------------------------------
template<int RELU, int OUTBF16, int SRCMODE>
__global__ __launch_bounds__(256, 3)
void gemm_nt(const ushort* __restrict__ A, long long sA, int lda,
             const ushort* __restrict__ B, long long sB, int ldb,
             const void* __restrict__ Sp, long long sS, int ldS,
             void*       __restrict__ O,  long long sO, int ldc,
             int K)
{
  __shared__ __align__(16) ushort lA[128*40];   // stride 40 (80B) -> <=2-way bank aliasing
  __shared__ __align__(16) ushort lB[128*40];

  const int z = blockIdx.z;
  const ushort* Ab = A + (long long)z*sA + (long long)blockIdx.y*128*lda;
  const ushort* Bb = B + (long long)z*sB + (long long)blockIdx.x*128*ldb;

  const int t    = threadIdx.x;
  const int lane = t & 63, wave = t >> 6;
  const int wm = (wave >> 1)*64, wn = (wave & 1)*64;
  const int lr = lane & 15, lq = lane >> 4;

  // staging map: vector v (8 bf16 = 16B): row = v>>2, col = (v&3)*8 ; v = t and t+256
  const int r0 = t >> 2, c0 = (t & 3)*8;
  const int r1 = r0 + 64;

  const ushort* pa0 = Ab + (long long)r0*lda + c0;
  const ushort* pa1 = Ab + (long long)r1*lda + c0;
  const ushort* pb0 = Bb + (long long)r0*ldb + c0;
  const ushort* pb1 = Bb + (long long)r1*ldb + c0;

  f32x4 acc[4][4] = {};

  short8 a0 = *(const short8*)pa0;
  short8 a1 = *(const short8*)pa1;
  short8 b0 = *(const short8*)pb0;
  short8 b1 = *(const short8*)pb1;

  int k0 = 0;
  for (;;) {
    __syncthreads();
    *(short8*)&lA[r0*40 + c0] = a0;
    *(short8*)&lA[r1*40 + c0] = a1;
    *(short8*)&lB[r0*40 + c0] = b0;
    *(short8*)&lB[r1*40 + c0] = b1;
    __syncthreads();
    k0 += 32;
    const bool more = (k0 < K);
    if (more) {                      // prefetch next K-tile; overlaps with MFMA below
      a0 = *(const short8*)(pa0 + k0);
      a1 = *(const short8*)(pa1 + k0);
      b0 = *(const short8*)(pb0 + k0);
      b1 = *(const short8*)(pb1 + k0);
    }
    bf16x8 af[4], bfr[4];
    #pragma unroll
    for (int i = 0; i < 4; i++) {
      af[i]  = *(const bf16x8*)&lA[(wm + i*16 + lr)*40 + lq*8];
      bfr[i] = *(const bf16x8*)&lB[(wn + i*16 + lr)*40 + lq*8];
    }
    #pragma unroll
    for (int i = 0; i < 4; i++)
      #pragma unroll
      for (int j = 0; j < 4; j++)
        acc[i][j] = __builtin_amdgcn_mfma_f32_16x16x32_bf16(af[i], bfr[j], acc[i][j], 0, 0, 0);
    if (!more) break;
  }

  // epilogue: D row = (lane>>4)*4 + reg, col = lane&15  [verified C/D layout]
  const int rowb = blockIdx.y*128 + wm + lq*4;
  const int colb = blockIdx.x*128 + wn + lr;
  #pragma unroll
  for (int i = 0; i < 4; i++) {
    #pragma unroll
    for (int j = 0; j < 4; j++) {
      const int col = colb + j*16;
      #pragma unroll
      for (int r = 0; r < 4; r++) {
        const int row = rowb + i*16 + r;
        float v = acc[i][j][r];
        if (RELU) v = fmaxf(v, 0.0f);
        if (SRCMODE == 1)
          v += bf2f(((const ushort*)Sp)[(long long)z*sS + (long long)row*ldS + col]);
        else if (SRCMODE == 2)
          v += ((const float*)Sp)[(long long)z*sS + (long long)row*ldS + col];
        if (OUTBF16)
          ((ushort*)O)[(long long)z*sO + (long long)row*ldc + col] = f2bf(v);
        else
          ((float*)O)[(long long)z*sO + (long long)row*ldc + col] = v;
      }
    }
  }
}

// ---------------------------------------------------------------------------
// row softmax over 256-wide rows: fp32 in -> bf16 out. one wave per row.
// ---------------------------------------------------------------------------
__global__ void softmax_bf16(const float* __restrict__ in, ushort* __restrict__ out)
{
  const int row  = blockIdx.x*4 + (threadIdx.x >> 6);
  const int lane = threadIdx.x & 63;
  const float4 v = ((const float4*)(in + (long long)row*256))[lane];
  float m = fmaxf(fmaxf(v.x, v.y), fmaxf(v.z, v.w));
  #pragma unroll
  for (int off = 32; off; off >>= 1) m = fmaxf(m, __shfl_xor(m, off, 64));
  float e0 = __expf(v.x - m), e1 = __expf(v.y - m), e2 = __expf(v.z - m), e3 = __expf(v.w - m);
  float s = e0 + e1 + e2 + e3;
  #pragma unroll
  for (int off = 32; off; off >>= 1) s += __shfl_xor(s, off, 64);
  const float inv = 1.0f / s;
  ushort4 o;
  o.x = f2bf(e0*inv); o.y = f2bf(e1*inv); o.z = f2bf(e2*inv); o.w = f2bf(e3*inv);
  ((ushort4*)(out + (long long)row*256))[lane] = o;
}

// ---------------------------------------------------------------------------
// prep kernels
// ---------------------------------------------------------------------------
__global__ void cast_bf16_kernel(const float* __restrict__ in, ushort* __restrict__ out, int n4)
{
  const int i = blockIdx.x*256 + threadIdx.x;
  if (i >= n4) return;
  const float4 v = ((const float4*)in)[i];
  ushort4 o; o.x = f2bf(v.x); o.y = f2bf(v.y); o.z = f2bf(v.z); o.w = f2bf(v.w);
  ((ushort4*)out)[i] = o;
}

struct P9 { const float* p[9]; };

// W (in=512, out=512) -> Wt (out, in) bf16, per blockIdx.z weight
__global__ void transcast_w(P9 ps, ushort* __restrict__ out)
{
  __shared__ float tile[32][33];
  const float* in = ps.p[blockIdx.z];
  ushort* o = out + (long long)blockIdx.z*262144;
  const int bo = blockIdx.x*32, bk = blockIdx.y*32;
  const int tx = threadIdx.x, ty = threadIdx.y;
  #pragma unroll
  for (int r = 0; r < 32; r += 8) tile[ty+r][tx] = in[(long long)(bk+ty+r)*512 + bo+tx];
  __syncthreads();
  #pragma unroll
  for (int r = 0; r < 32; r += 8) o[(long long)(bo+ty+r)*512 + bk+tx] = f2bf(tile[tx][ty+r]);
}

// adj (B,256,256) fp32 -> adj bf16 and adjT bf16
__global__ void prep_adj(const float* __restrict__ adj, ushort* __restrict__ ab, ushort* __restrict__ atb)
{
  __shared__ float tile[32][33];
  const long long base = (long long)blockIdx.z*65536;
  const int bi = blockIdx.y*32, bj = blockIdx.x*32;
  const int tx = threadIdx.x, ty = threadIdx.y;
  #pragma unroll
  for (int r = 0; r < 32; r += 8) {
    const float v = adj[base + (long long)(bi+ty+r)*256 + bj+tx];
    tile[ty+r][tx] = v;
    ab[base + (long long)(bi+ty+r)*256 + bj+tx] = f2bf(v);
  }
  __syncthreads();
  #pragma unroll
  for (int r = 0; r < 32; r += 8)
    atb[base + (long long)(bj+ty+r)*256 + bi+tx] = f2bf(tile[tx][ty+r]);
}

// ---------------------------------------------------------------------------
#define GEMM(RELU, OB, SM, Ap, sa, la, Bp, sb, lb, Srcp, ss, ls, Op, so, lc, M, Nn, Kk) \
  gemm_nt<RELU, OB, SM><<<dim3((Nn)/128, (M)/128, 64), 256, 0, stream>>>( \
    (const ushort*)(Ap), (long long)(sa), (la), (const ushort*)(Bp), (long long)(sb), (lb), \
    (const void*)(Srcp), (long long)(ss), (ls), (void*)(Op), (long long)(so), (lc), (Kk))

extern "C" void kernel_launch(void* const* d_in, const int* in_sizes, int n_in,
                              void* d_out, int out_size, void* d_ws, size_t ws_size,
                              hipStream_t stream)
{
  (void)in_sizes; (void)n_in; (void)out_size;
  const float* F    = (const float*)d_in[0];
  const float* ADJ  = (const float*)d_in[2];
  const float* Wse1 = (const float*)d_in[3];
  const float* Wse2 = (const float*)d_in[4];

  uint8_t* w = (uint8_t*)d_ws;
  size_t off = 0;
  auto alloc = [&](size_t bytes) -> void* { void* p = w + off; off += (bytes + 255) & ~(size_t)255; return p; };

  ushort* WSE1 = (ushort*)alloc(524288);        // 512x512 bf16
  ushort* WSE2 = (ushort*)alloc(524288);
  ushort* WT   = (ushort*)alloc(9*524288);      // 9 transposed weights bf16
  ushort* FB   = (ushort*)alloc(16777216);      // f bf16 (B,N,C)
  ushort* ADJB = (ushort*)alloc(8388608);       // adj bf16
  ushort* ADJT = (ushort*)alloc(8388608);       // adjT bf16
  ushort* Sb   = (ushort*)alloc(8388608);       // S bf16 (B,N,N)
  float*  SC32 = (float*)alloc(16777216);       // Sc fp32 (B,N,N); reused as B4 later
  ushort* B4   = (ushort*)SC32;
  ushort* B1   = (ushort*)alloc(16777216);      // (B, N*C) bf16 generic
  ushort* B2   = (ushort*)alloc(16777216);
  ushort* B3   = (ushort*)alloc(16777216);
  if (off > ws_size) return;  // workspace too small; bench will fail loudly

  // ---- prep: casts / transposes ----
  cast_bf16_kernel<<<8192, 256, 0, stream>>>(F, FB, 2097152);
  cast_bf16_kernel<<<256, 256, 0, stream>>>(Wse1, WSE1, 65536);
  cast_bf16_kernel<<<256, 256, 0, stream>>>(Wse2, WSE2, 65536);
  P9 ps; for (int k = 0; k < 9; k++) ps.p[k] = (const float*)d_in[5 + k];
  transcast_w<<<dim3(16,16,9), dim3(32,8), 0, stream>>>(ps, WT);
  prep_adj<<<dim3(8,8,64), dim3(32,8), 0, stream>>>(ADJ, ADJB, ADJT);

  const long long sNC = 131072, sNN = 65536;

  // ---- similarity graph: S = softmax((f Wse1^T)(f Wse2^T)^T) ----
  GEMM(0,1,0, FB,sNC,512, WSE1,0,512, nullptr,0,0, B1,sNC,512, 256,512,512);   // T1
  GEMM(0,1,0, FB,sNC,512, WSE2,0,512, nullptr,0,0, B2,sNC,512, 256,512,512);   // T2
  GEMM(0,0,0, B1,sNC,512, B2,sNC,512, nullptr,0,0, SC32,sNN,256, 256,256,512); // Sc (fp32)
  softmax_bf16<<<4096, 256, 0, stream>>>(SC32, Sb);

  // ---- sim_GCN (YT = Wt . x^T form; G = relu(S . YT)) ----
  GEMM(0,1,0, WT+6*262144,0,512, FB,sNC,512, nullptr,0,0, B1,sNC,256, 512,256,512); // YT sim1
  GEMM(1,1,0, Sb,sNN,256, B1,sNC,256, nullptr,0,0, B2,sNC,512, 256,512,256);        // G1
  GEMM(0,1,0, WT+7*262144,0,512, B2,sNC,512, nullptr,0,0, B1,sNC,256, 512,256,512); // YT sim2
  GEMM(1,1,0, Sb,sNN,256, B1,sNC,256, nullptr,0,0, B3,sNC,512, 256,512,256);        // G2
  GEMM(0,1,0, WT+8*262144,0,512, B3,sNC,512, nullptr,0,0, B1,sNC,256, 512,256,512); // YT sim3 (hold B1)

  // ---- st_GCN layer 1 ----
  GEMM(0,1,0, WT+0*262144,0,512, FB,sNC,512, nullptr,0,0, B2,sNC,256, 512,256,512); // YTf1
  GEMM(0,1,0, WT+3*262144,0,512, FB,sNC,512, nullptr,0,0, B3,sNC,256, 512,256,512); // YTb1
  GEMM(1,1,0, ADJB,sNN,256, B2,sNC,256, nullptr,0,0, B4,sNC,512, 256,512,256);      // relu(adj.Yf)
  GEMM(1,1,1, ADJT,sNN,256, B3,sNC,256, B4,sNC,512, B4,sNC,512, 256,512,256);       // += relu(adjT.Yb)
  // ---- layer 2 ----
  GEMM(0,1,0, WT+1*262144,0,512, B4,sNC,512, nullptr,0,0, B2,sNC,256, 512,256,512);
  GEMM(0,1,0, WT+4*262144,0,512, B4,sNC,512, nullptr,0,0, B3,sNC,256, 512,256,512);
  GEMM(1,1,0, ADJB,sNN,256, B2,sNC,256, nullptr,0,0, FB,sNC,512, 256,512,256);      // H2 -> FB (f dead)
  GEMM(1,1,1, ADJT,sNN,256, B3,sNC,256, FB,sNC,512, FB,sNC,512, 256,512,256);
  // ---- layer 3 (fp32 into d_out) ----
  GEMM(0,1,0, WT+2*262144,0,512, FB,sNC,512, nullptr,0,0, B2,sNC,256, 512,256,512);
  GEMM(0,1,0, WT+5*262144,0,512, FB,sNC,512, nullptr,0,0, B3,sNC,256, 512,256,512);
  GEMM(1,0,0, ADJB,sNN,256, B2,sNC,256, nullptr,0,0, d_out,sNC,512, 256,512,256);   // st  = relu(adj.Yf)
  GEMM(1,0,2, ADJT,sNN,256, B3,sNC,256, d_out,sNC,512, d_out,sNC,512, 256,512,256); // st += relu(adjT.Yb)

  // ---- final: out = st + relu(S . YT_sim3) ----
  GEMM(1,0,2, Sb,sNN,256, B1,sNC,256, d_out,sNC,512, d_out,sNC,512, 256,512,256);
}

// Round 2
// 443.203 us; speedup vs baseline: 1.0946x; 1.0946x over previous
//
#include <hip/hip_runtime.h>
#include <stdint.h>

#define DEVI __device__ __forceinline__

using bf16x8 = __attribute__((ext_vector_type(8))) __bf16;
using f32x4  = __attribute__((ext_vector_type(4))) float;

DEVI ushort f2bf(float f){
  uint32_t u = __float_as_uint(f);
  uint32_t r = u + 0x7fffu + ((u >> 16) & 1u);   // RNE
  return (ushort)(r >> 16);
}
DEVI float bf2f(ushort h){ return __uint_as_float(((uint32_t)h) << 16); }

// async 16B global -> LDS (wave-uniform LDS base; lane lands at base + lane*16)
DEVI void async16(const ushort* g, ushort* l, int lbyte) {
  __builtin_amdgcn_global_load_lds(
      (const __attribute__((address_space(1))) uint32_t*)g,
      (__attribute__((address_space(3))) uint32_t*)((char*)l + lbyte),
      16, 0, 0);
}

// ---------------------------------------------------------------------------
// NT GEMM: D[m,n] = sum_k A[m,k]*B[n,k].  Tile 128x128, BK=32, 256 thr, m97-
// style global_load_lds staging (unpadded 128x32 LDS tiles, 2-barrier K loop).
// SRCMODE: 0=none, 1=add bf16 src, 2=add f32 src.  out = [src +] relu?(acc)
// ---------------------------------------------------------------------------
template<int RELU, int OUTBF16, int SRCMODE>
__global__ __launch_bounds__(256, 3)
void gemm_nt(const ushort* __restrict__ A, long long sA, int lda,
             const ushort* __restrict__ B, long long sB, int ldb,
             const void* __restrict__ Sp, long long sS, int ldS,
             void*       __restrict__ O,  long long sO, int ldc,
             int K)
{
  __shared__ __align__(16) ushort lA[128*32];
  __shared__ __align__(16) ushort lB[128*32];

  const int z = blockIdx.z;
  const ushort* Ab = A + (long long)z*sA + (long long)blockIdx.y*128*lda;
  const ushort* Bb = B + (long long)z*sB + (long long)blockIdx.x*128*ldb;

  const int t = threadIdx.x, lane = t & 63, wave = t >> 6;
  const int wm = (wave >> 1)*64, wn = (wave & 1)*64;
  const int lr = lane & 15, lq = lane >> 4;

  // staging map: vector v in [0,512): row=v>>2, col=(v&3)*8; lds byte = v*16
  const int r0 = t >> 2, c0 = (t & 3)*8;
  const int lb0 = __builtin_amdgcn_readfirstlane((t & 192) * 16);
  const int lb1 = lb0 + 4096;
  const ushort* pa = Ab + (long long)r0*lda + c0;
  const ushort* pb = Bb + (long long)r0*ldb + c0;
  const long long a64 = (long long)64*lda, b64 = (long long)64*ldb;

  f32x4 acc[4][4] = {};

  for (int k0 = 0; k0 < K; k0 += 32) {
    __syncthreads();                       // LDS free (prev ds_reads done)
    async16(pa + k0,       lA, lb0);
    async16(pa + a64 + k0, lA, lb1);
    async16(pb + k0,       lB, lb0);
    async16(pb + b64 + k0, lB, lb1);
    __syncthreads();                       // vmcnt(0) drain -> tiles visible
    bf16x8 af[4], bfr[4];
    #pragma unroll
    for (int i = 0; i < 4; i++) {
      af[i]  = *(const bf16x8*)&lA[(wm + i*16 + lr)*32 + lq*8];
      bfr[i] = *(const bf16x8*)&lB[(wn + i*16 + lr)*32 + lq*8];
    }
    #pragma unroll
    for (int i = 0; i < 4; i++)
      #pragma unroll
      for (int j = 0; j < 4; j++)
        acc[i][j] = __builtin_amdgcn_mfma_f32_16x16x32_bf16(af[i], bfr[j], acc[i][j], 0, 0, 0);
  }

  // epilogue: D row = (lane>>4)*4 + reg, col = lane&15
  const int rowb = blockIdx.y*128 + wm + lq*4;
  const int colb = blockIdx.x*128 + wn + lr;
  #pragma unroll
  for (int i = 0; i < 4; i++) {
    #pragma unroll
    for (int j = 0; j < 4; j++) {
      const int col = colb + j*16;
      #pragma unroll
      for (int r = 0; r < 4; r++) {
        const int row = rowb + i*16 + r;
        float v = acc[i][j][r];
        if (RELU) v = fmaxf(v, 0.0f);
        if (SRCMODE == 1)
          v += bf2f(((const ushort*)Sp)[(long long)z*sS + (long long)row*ldS + col]);
        else if (SRCMODE == 2)
          v += ((const float*)Sp)[(long long)z*sS + (long long)row*ldS + col];
        if (OUTBF16)
          ((ushort*)O)[(long long)z*sO + (long long)row*ldc + col] = f2bf(v);
        else
          ((float*)O)[(long long)z*sO + (long long)row*ldc + col] = v;
      }
    }
  }
}

// ---------------------------------------------------------------------------
// Dual-branch adjacency GEMM: O = relu(adj @ Yf) + relu(adjT @ Yb), bf16 out.
// A1=adj, A2=adjT: (z,256,256) ld 256. B: stacked YT (z,1024,256) rows 0-511
// = Yf^T, 512-1023 = Yb^T. O: (z,256,512). Tile 128x128, K=256.
// ---------------------------------------------------------------------------
__global__ __launch_bounds__(256, 2)
void gemm_dual(const ushort* __restrict__ A1, const ushort* __restrict__ A2,
               const ushort* __restrict__ B,  ushort* __restrict__ O)
{
  __shared__ __align__(16) ushort lA1[128*32];
  __shared__ __align__(16) ushort lA2[128*32];
  __shared__ __align__(16) ushort lB1[128*32];
  __shared__ __align__(16) ushort lB2[128*32];

  const int z = blockIdx.z;
  const ushort* A1b = A1 + (long long)z*65536 + (long long)blockIdx.y*128*256;
  const ushort* A2b = A2 + (long long)z*65536 + (long long)blockIdx.y*128*256;
  const ushort* B1b = B  + (long long)z*262144 + (long long)blockIdx.x*128*256;
  const ushort* B2b = B1b + 131072;

  const int t = threadIdx.x, lane = t & 63, wave = t >> 6;
  const int wm = (wave >> 1)*64, wn = (wave & 1)*64;
  const int lr = lane & 15, lq = lane >> 4;

  const int r0 = t >> 2, c0 = (t & 3)*8;
  const int lb0 = __builtin_amdgcn_readfirstlane((t & 192) * 16);
  const int lb1 = lb0 + 4096;
  const ushort* p1 = A1b + (long long)r0*256 + c0;
  const ushort* p2 = A2b + (long long)r0*256 + c0;
  const ushort* p3 = B1b + (long long)r0*256 + c0;
  const ushort* p4 = B2b + (long long)r0*256 + c0;
  const int roff = 64*256;

  f32x4 acc1[4][4] = {}, acc2[4][4] = {};

  for (int k0 = 0; k0 < 256; k0 += 32) {
    __syncthreads();
    async16(p1 + k0,        lA1, lb0);
    async16(p1 + roff + k0, lA1, lb1);
    async16(p2 + k0,        lA2, lb0);
    async16(p2 + roff + k0, lA2, lb1);
    async16(p3 + k0,        lB1, lb0);
    async16(p3 + roff + k0, lB1, lb1);
    async16(p4 + k0,        lB2, lb0);
    async16(p4 + roff + k0, lB2, lb1);
    __syncthreads();
    {
      bf16x8 af[4], bfr[4];
      #pragma unroll
      for (int i = 0; i < 4; i++) {
        af[i]  = *(const bf16x8*)&lA1[(wm + i*16 + lr)*32 + lq*8];
        bfr[i] = *(const bf16x8*)&lB1[(wn + i*16 + lr)*32 + lq*8];
      }
      #pragma unroll
      for (int i = 0; i < 4; i++)
        #pragma unroll
        for (int j = 0; j < 4; j++)
          acc1[i][j] = __builtin_amdgcn_mfma_f32_16x16x32_bf16(af[i], bfr[j], acc1[i][j], 0, 0, 0);
    }
    {
      bf16x8 af[4], bfr[4];
      #pragma unroll
      for (int i = 0; i < 4; i++) {
        af[i]  = *(const bf16x8*)&lA2[(wm + i*16 + lr)*32 + lq*8];
        bfr[i] = *(const bf16x8*)&lB2[(wn + i*16 + lr)*32 + lq*8];
      }
      #pragma unroll
      for (int i = 0; i < 4; i++)
        #pragma unroll
        for (int j = 0; j < 4; j++)
          acc2[i][j] = __builtin_amdgcn_mfma_f32_16x16x32_bf16(af[i], bfr[j], acc2[i][j], 0, 0, 0);
    }
  }

  const int rowb = blockIdx.y*128 + wm + lq*4;
  const int colb = blockIdx.x*128 + wn + lr;
  #pragma unroll
  for (int i = 0; i < 4; i++)
    #pragma unroll
    for (int j = 0; j < 4; j++)
      #pragma unroll
      for (int r = 0; r < 4; r++) {
        float v = fmaxf(acc1[i][j][r], 0.0f) + fmaxf(acc2[i][j][r], 0.0f);
        O[(long long)z*131072 + (long long)(rowb + i*16 + r)*512 + colb + j*16] = f2bf(v);
      }
}

// ---------------------------------------------------------------------------
// row softmax over 256-wide rows: fp32 in -> bf16 out. one wave per row.
// ---------------------------------------------------------------------------
__global__ void softmax_bf16(const float* __restrict__ in, ushort* __restrict__ out)
{
  const int row  = blockIdx.x*4 + (threadIdx.x >> 6);
  const int lane = threadIdx.x & 63;
  const float4 v = ((const float4*)(in + (long long)row*256))[lane];
  float m = fmaxf(fmaxf(v.x, v.y), fmaxf(v.z, v.w));
  #pragma unroll
  for (int off = 32; off; off >>= 1) m = fmaxf(m, __shfl_xor(m, off, 64));
  float e0 = __expf(v.x - m), e1 = __expf(v.y - m), e2 = __expf(v.z - m), e3 = __expf(v.w - m);
  float s = e0 + e1 + e2 + e3;
  #pragma unroll
  for (int off = 32; off; off >>= 1) s += __shfl_xor(s, off, 64);
  const float inv = 1.0f / s;
  ushort4 o;
  o.x = f2bf(e0*inv); o.y = f2bf(e1*inv); o.z = f2bf(e2*inv); o.w = f2bf(e3*inv);
  ((ushort4*)(out + (long long)row*256))[lane] = o;
}

// ---------------------------------------------------------------------------
// prep kernels
// ---------------------------------------------------------------------------
__global__ void cast_bf16_kernel(const float* __restrict__ in, ushort* __restrict__ out, int n4)
{
  const int i = blockIdx.x*256 + threadIdx.x;
  if (i >= n4) return;
  const float4 v = ((const float4*)in)[i];
  ushort4 o; o.x = f2bf(v.x); o.y = f2bf(v.y); o.z = f2bf(v.z); o.w = f2bf(v.w);
  ((ushort4*)out)[i] = o;
}

struct P11 { const float* p[11]; };

// W (512x512 row-major) -> W^T bf16, per blockIdx.z weight (slot order from ps)
__global__ void transcast_w(P11 ps, ushort* __restrict__ out)
{
  __shared__ float tile[32][33];
  const float* in = ps.p[blockIdx.z];
  ushort* o = out + (long long)blockIdx.z*262144;
  const int bo = blockIdx.x*32, bk = blockIdx.y*32;
  const int tx = threadIdx.x, ty = threadIdx.y;
  #pragma unroll
  for (int r = 0; r < 32; r += 8) tile[ty+r][tx] = in[(long long)(bk+ty+r)*512 + bo+tx];
  __syncthreads();
  #pragma unroll
  for (int r = 0; r < 32; r += 8) o[(long long)(bo+ty+r)*512 + bk+tx] = f2bf(tile[tx][ty+r]);
}

// adj (B,256,256) fp32 -> adj bf16 and adjT bf16
__global__ void prep_adj(const float* __restrict__ adj, ushort* __restrict__ ab, ushort* __restrict__ atb)
{
  __shared__ float tile[32][33];
  const long long base = (long long)blockIdx.z*65536;
  const int bi = blockIdx.y*32, bj = blockIdx.x*32;
  const int tx = threadIdx.x, ty = threadIdx.y;
  #pragma unroll
  for (int r = 0; r < 32; r += 8) {
    const float v = adj[base + (long long)(bi+ty+r)*256 + bj+tx];
    tile[ty+r][tx] = v;
    ab[base + (long long)(bi+ty+r)*256 + bj+tx] = f2bf(v);
  }
  __syncthreads();
  #pragma unroll
  for (int r = 0; r < 32; r += 8)
    atb[base + (long long)(bj+ty+r)*256 + bi+tx] = f2bf(tile[tx][ty+r]);
}

// ---------------------------------------------------------------------------
#define GEMM(RELU, OB, SM, Ap, sa, la, Bp, sb, lb, Srcp, ss, ls, Op, so, lc, M, Nn, Kk, Z) \
  gemm_nt<RELU, OB, SM><<<dim3((Nn)/128, (M)/128, (Z)), 256, 0, stream>>>( \
    (const ushort*)(Ap), (long long)(sa), (la), (const ushort*)(Bp), (long long)(sb), (lb), \
    (const void*)(Srcp), (long long)(ss), (ls), (void*)(Op), (long long)(so), (lc), (Kk))

extern "C" void kernel_launch(void* const* d_in, const int* in_sizes, int n_in,
                              void* d_out, int out_size, void* d_ws, size_t ws_size,
                              hipStream_t stream)
{
  (void)in_sizes; (void)n_in; (void)out_size;
  const float* F   = (const float*)d_in[0];
  const float* ADJ = (const float*)d_in[2];

  uint8_t* w = (uint8_t*)d_ws;
  size_t off = 0;
  auto alloc = [&](size_t bytes) -> void* { void* p = w + off; off += (bytes + 255) & ~(size_t)255; return p; };

  const long long SL = 262144;                   // 512x512 bf16 elements
  ushort* WT   = (ushort*)alloc(11*524288);      // transposed weights bf16 (slots below)
  ushort* WMT  = (ushort*)alloc(524288);         // WmidT = (Wse1^T Wse2)^T bf16
  ushort* FB   = (ushort*)alloc(16777216);       // f bf16 (B,N,C)
  ushort* ADJB = (ushort*)alloc(8388608);
  ushort* ADJT = (ushort*)alloc(8388608);
  ushort* TB   = (ushort*)alloc(16777216);       // T = f @ Wmid, bf16 (B,N,C)
  float*  SC32 = (float*)alloc(16777216);        // Sc fp32 (B,N,N)
  ushort* Sb   = (ushort*)alloc(8388608);        // S bf16 (B,N,N)
  ushort* YTB  = (ushort*)alloc(33554432);       // stacked st YT (B,1024,256)
  ushort* SY   = (ushort*)alloc(16777216);       // sim YT (B,512,256)
  ushort* Gb   = (ushort*)alloc(16777216);       // sim hidden (B,N,C)
  ushort* Hb   = (ushort*)alloc(16777216);       // st hidden / st result (B,N,C)
  if (off > ws_size) return;

  const long long sNC = 131072, sNN = 65536, sYT = 262144, sSY = 131072;

  // ---- prep ----
  cast_bf16_kernel<<<8192, 256, 0, stream>>>(F, FB, 2097152);
  // slots: 0:Wst1 1:Wst1b 2:Wst2 3:Wst2b 4:Wst3 5:Wst3b 6..8:Wsim1..3 9:Wse1T 10:Wse2T
  P11 ps;
  ps.p[0] = (const float*)d_in[5];  ps.p[1] = (const float*)d_in[8];
  ps.p[2] = (const float*)d_in[6];  ps.p[3] = (const float*)d_in[9];
  ps.p[4] = (const float*)d_in[7];  ps.p[5] = (const float*)d_in[10];
  ps.p[6] = (const float*)d_in[11]; ps.p[7] = (const float*)d_in[12];
  ps.p[8] = (const float*)d_in[13];
  ps.p[9] = (const float*)d_in[3];  ps.p[10] = (const float*)d_in[4];
  transcast_w<<<dim3(16,16,11), dim3(32,8), 0, stream>>>(ps, WT);
  prep_adj<<<dim3(8,8,64), dim3(32,8), 0, stream>>>(ADJ, ADJB, ADJT);

  // ---- similarity: WmidT = gemm_nt(Wse2T, Wse1T); T = f@Wmid; Sc = T@f^T ----
  GEMM(0,1,0, WT+10*SL,0,512, WT+9*SL,0,512, nullptr,0,0, WMT,0,512, 512,512,512, 1);
  GEMM(0,1,0, FB,sNC,512, WMT,0,512, nullptr,0,0, TB,sNC,512, 256,512,512, 64);
  GEMM(0,0,0, TB,sNC,512, FB,sNC,512, nullptr,0,0, SC32,sNN,256, 256,256,512, 64);
  softmax_bf16<<<4096, 256, 0, stream>>>(SC32, Sb);

  // ---- sim_GCN ----
  GEMM(0,1,0, WT+6*SL,0,512, FB,sNC,512, nullptr,0,0, SY,sSY,256, 512,256,512, 64);
  GEMM(1,1,0, Sb,sNN,256, SY,sSY,256, nullptr,0,0, Gb,sNC,512, 256,512,256, 64);
  GEMM(0,1,0, WT+7*SL,0,512, Gb,sNC,512, nullptr,0,0, SY,sSY,256, 512,256,512, 64);
  GEMM(1,1,0, Sb,sNN,256, SY,sSY,256, nullptr,0,0, Gb,sNC,512, 256,512,256, 64);
  GEMM(0,1,0, WT+8*SL,0,512, Gb,sNC,512, nullptr,0,0, SY,sSY,256, 512,256,512, 64);  // hold SY

  // ---- st_GCN: stacked YT + dual adjacency per layer ----
  GEMM(0,1,0, WT+0*SL,0,512, FB,sNC,512, nullptr,0,0, YTB,sYT,256, 1024,256,512, 64);
  gemm_dual<<<dim3(4,2,64), 256, 0, stream>>>(ADJB, ADJT, YTB, Hb);
  GEMM(0,1,0, WT+2*SL,0,512, Hb,sNC,512, nullptr,0,0, YTB,sYT,256, 1024,256,512, 64);
  gemm_dual<<<dim3(4,2,64), 256, 0, stream>>>(ADJB, ADJT, YTB, Hb);
  GEMM(0,1,0, WT+4*SL,0,512, Hb,sNC,512, nullptr,0,0, YTB,sYT,256, 1024,256,512, 64);
  gemm_dual<<<dim3(4,2,64), 256, 0, stream>>>(ADJB, ADJT, YTB, Hb);

  // ---- final: out = st + relu(S @ Ysim3)  (fp32) ----
  GEMM(1,0,1, Sb,sNN,256, SY,sSY,256, Hb,sNC,512, d_out,sNC,512, 256,512,256, 64);
}